// Round 1
// 760.123 us; speedup vs baseline: 1.1431x; 1.1431x over previous
//
#include <hip/hip_runtime.h>

// Monte-Carlo (stochastic) 2x2 pooling.
// Reference: per 2x2 block, idx = argmax_k( log(max(x_k,EPS)) + gumbel(u_k) ),
//            gumbel(u) = -log(-log(clip(u, EPS, 1-EPS))).
// Monotone-transform equivalence: argmax of log(x'_k) - log(w_k) with
// w_k = -log(clip(u_k)) > 0  ==  argmax of x'_k / w_k, resolved via
// cross-multiplication (preserves argmax's first-index tie-break with a
// strict '>' ascending scan).
//
// This version does the whole decision in f32 (logf + f32 products) and falls
// back to the previous exact double path ONLY when a comparison is within a
// conservative relative margin (2e-6). Error budget for the f32 path:
//   logf (OCML)            <= ~2.4e-7 rel
//   clip const 1e-12f/1e-12 <= ~6e-8 rel (only when x or u == 0)
//   product rounding        <= ~1.2e-7 rel
//   total per side          <= ~4.4e-7 rel  << 2e-6 margin
// So any decision taken on the fast path agrees with the exact double result;
// ambiguous cases (expected O(tens) out of 25.7M) rerun the double code,
// which is bit-identical to the previously passing kernel.
//
// Shapes: x (32,64,224,224) f32, u (32,64,112,112,4) f32, out (32,64,112,112) f32.

#define PH 112
#define PW 112
#define EPS 1e-12

__global__ __launch_bounds__(256) void mc_pool_kernel(const float* __restrict__ x,
                                                      const float* __restrict__ u,
                                                      float* __restrict__ out,
                                                      int n_out) {
    int o = blockIdx.x * blockDim.x + threadIdx.x;
    if (o >= n_out) return;

    int j  = o % PW;          // pooled col
    int t  = o / PW;
    int i  = t % PH;          // pooled row
    int bc = t / PH;          // fused batch*channel

    // x as float2: each (b,c) image is 224*224 floats = 25088 float2;
    // row 2i starts at float2 offset bc*25088 + i*224. Block rows 2i, 2i+1.
    const float2* __restrict__ x2 = (const float2*)x;
    long base = (long)bc * 25088 + (long)i * 224 + j;
    float2 ra = x2[base];         // x[2i][2j], x[2i][2j+1]
    float2 rb = x2[base + 112];   // x[2i+1][2j], x[2i+1][2j+1]

    // u: 4 contiguous floats per output, same (p0,p1) flatten order as block.
    const float4* __restrict__ u4p = (const float4*)u;
    float4 uu = u4p[o];

    // ---------------- fast path: all-f32 ----------------
    // u < 1.0 always (uniform [0,1) in f32 has max 1-2^-24), so the upper
    // clip at 1-1e-12 is inactive; only the lower clip matters.
    float xf[4] = { fmaxf(ra.x, 1e-12f), fmaxf(ra.y, 1e-12f),
                    fmaxf(rb.x, 1e-12f), fmaxf(rb.y, 1e-12f) };
    float uf[4] = { uu.x, uu.y, uu.z, uu.w };
    float wf[4];
#pragma unroll
    for (int k = 0; k < 4; ++k) {
        float uc = fmaxf(uf[k], 1e-12f);
        wf[k] = -logf(uc);    // > 0 since uc < 1
    }

    int best = 0;
    bool unsure = false;
#pragma unroll
    for (int k = 1; k < 4; ++k) {
        float a = xf[k] * wf[best];
        float b = xf[best] * wf[k];
        // products are strictly positive; relative-margin ambiguity test
        if (fabsf(a - b) <= 2e-6f * fmaxf(a, b)) unsure = true;
        if (a > b) best = k;
    }

    // ------------- exact fallback: double (rare) -------------
    if (__builtin_expect(unsure, 0)) {
        double xv[4] = { fmax((double)ra.x, EPS), fmax((double)ra.y, EPS),
                         fmax((double)rb.x, EPS), fmax((double)rb.y, EPS) };
        double w[4];
#pragma unroll
        for (int k = 0; k < 4; ++k) {
            double uc = fmin(fmax((double)uf[k], EPS), 1.0 - EPS);
            w[k] = -log(uc);
        }
        best = 0;
#pragma unroll
        for (int k = 1; k < 4; ++k) {
            if (xv[k] * w[best] > xv[best] * w[k]) best = k;
        }
    }

    out[o] = (float)best;
}

extern "C" void kernel_launch(void* const* d_in, const int* in_sizes, int n_in,
                              void* d_out, int out_size, void* d_ws, size_t ws_size,
                              hipStream_t stream) {
    const float* x = (const float*)d_in[0];
    const float* u = (const float*)d_in[1];
    float* out = (float*)d_out;
    int n_out = out_size;  // 32*64*112*112 = 25,690,112
    int block = 256;
    int grid = (n_out + block - 1) / block;
    mc_pool_kernel<<<grid, block, 0, stream>>>(x, u, out, n_out);
}